// Round 10
// baseline (1261.226 us; speedup 1.0000x reference)
//
#include <hip/hip_runtime.h>

typedef int   i32x4 __attribute__((ext_vector_type(4)));
typedef float f32x4 __attribute__((ext_vector_type(4)));

// Problem constants
#define NB   64
#define NT   256
#define NC   512
#define NK   1024
#define NQ   6
#define NROWS (NB*NT)        // 16384
#define QOUT_ELEMS 8388608   // B*C*T
#define IDX_ELEMS  98304     // B*T*Q
#define DELTA 10.0f          // candidate window (~8 sigma of i8 512-term dot error @ worst layer)
#define CAP  64              // candidate slots per row (uint2 pairs); overflow -> full rescan

// ws layout (bytes)
#define WS_CAND   0                        // uint2[16384*64] = 8 MiB
#define WS_CCNT   0x800000                 // u32[16384]
#define WS_BIDX   0x810000                 // i32[16384]
#define WS_COUNTS 0x820000                 // u32[1024]
#define WS_CSUM   0x821000                 // f32[6]
#define WS_CMEAN  0x821020                 // f32[6]
#define WS_PERP   0x821040                 // f32[6]
#define WS_DONE   0x821060                 // u32[1]
#define WS_RMAX   0x821080                 // u32[8]: float-bits maxabs of r_q (r_0 = x)
#define WS_CBN    0x822000                 // f32[6144] half-norms
#define WS_CBS    0x828000                 // f32[6144] per-code i8 scales
#define WS_XHI    0x830000                 // i8[8 panels][16384][64], 8 MiB (panel-major swizzled)
#define WS_CBHI   (WS_XHI + 8388608)       // i8[6][8 panels][1024][64], 3 MiB

// swizzle key for 16B chunks within a 64B row (consistent emit/read; bases mult of 64)
#define KEY4(r) (((r) + ((r) >> 2)) & 3)

// float -> i8 with clamp (RNE via rintf)
__device__ __forceinline__ unsigned pack4i8(float a, float b, float c, float d, float is) {
    int qa = (int)rintf(a * is), qb = (int)rintf(b * is);
    int qc = (int)rintf(c * is), qd = (int)rintf(d * is);
    qa = qa > 127 ? 127 : (qa < -127 ? -127 : qa);
    qb = qb > 127 ? 127 : (qb < -127 ? -127 : qb);
    qc = qc > 127 ? 127 : (qc < -127 ? -127 : qc);
    qd = qd > 127 ? 127 : (qd < -127 ? -127 : qd);
    return (qa & 0xff) | ((qb & 0xff) << 8) | ((qc & 0xff) << 16) | ((qd & 0xff) << 24);
}

__device__ __forceinline__ void load_lds16(const unsigned char* g, unsigned char* l) {
    __builtin_amdgcn_global_load_lds(
        (const __attribute__((address_space(1))) unsigned int*)g,
        (__attribute__((address_space(3))) unsigned int*)l,
        16, 0, 0);
}

// 32-bit LDS byte address for inline-asm DS ops
__device__ __forceinline__ unsigned lds_addr(const unsigned char* p) {
    return (unsigned)(unsigned long long)
        (const __attribute__((address_space(3))) unsigned char*)p;
}

// opaque ds_read_b128: compiler can't see the LDS dependency -> no auto vmcnt(0)
#define DSR(d, b, IMM) \
    asm volatile("ds_read_b128 %0, %1 offset:" #IMM : "=v"(d) : "v"(b))

// -------- global maxabs of x (runs once; rmax[0]) --------
__global__ __launch_bounds__(256) void vq_xmax(const float* __restrict__ x,
                                               unsigned* __restrict__ rmax) {
    __shared__ float wm[4];
    const int tid = threadIdx.x;
    float m = 0.f;
    for (int i = blockIdx.x * 256 + tid; i < QOUT_ELEMS / 4; i += 1024 * 256) {
        float4 v = ((const float4*)x)[i];
        m = fmaxf(m, fmaxf(fmaxf(fabsf(v.x), fabsf(v.y)), fmaxf(fabsf(v.z), fabsf(v.w))));
    }
    #pragma unroll
    for (int off = 32; off; off >>= 1) m = fmaxf(m, __shfl_down(m, off, 64));
    if ((tid & 63) == 0) wm[tid >> 6] = m;
    __syncthreads();
    if (tid == 0)
        atomicMax(rmax, __float_as_uint(fmaxf(fmaxf(wm[0], wm[1]), fmaxf(wm[2], wm[3]))));
}

// -------- codebook conversion (all 6 layers) to i8 + half-norms + scales ----
// PANEL-MAJOR swizzled: per layer [kk=0..7][code][4 chunks of 16B],
// chunk cq stored at slot cq^KEY4(code). Per-code scale = maxabs/127.
__global__ __launch_bounds__(256) void vq_cvt_cb(const float* __restrict__ cb,
                                                 unsigned char* __restrict__ cbhi,
                                                 float* __restrict__ cbn,
                                                 float* __restrict__ cbs) {
    int lane = threadIdx.x & 63, wid = threadIdx.x >> 6;
    int code = blockIdx.x * 4 + wid;                 // 0..6143
    int layer = code >> 10, cin = code & 1023;
    const float* row = cb + (size_t)code * NC;
    float4 v0 = *(const float4*)(row + lane * 8);
    float4 v1 = *(const float4*)(row + lane * 8 + 4);
    float s = v0.x*v0.x + v0.y*v0.y + v0.z*v0.z + v0.w*v0.w
            + v1.x*v1.x + v1.y*v1.y + v1.z*v1.z + v1.w*v1.w;
    float am = fmaxf(fmaxf(fmaxf(fabsf(v0.x), fabsf(v0.y)), fmaxf(fabsf(v0.z), fabsf(v0.w))),
                     fmaxf(fmaxf(fabsf(v1.x), fabsf(v1.y)), fmaxf(fabsf(v1.z), fabsf(v1.w))));
    #pragma unroll
    for (int off = 1; off < 64; off <<= 1) am = fmaxf(am, __shfl_xor(am, off, 64));
    float is = 127.0f / am;                          // gaussian rows: am > 0
    uint2 w;
    w.x = pack4i8(v0.x, v0.y, v0.z, v0.w, is);
    w.y = pack4i8(v1.x, v1.y, v1.z, v1.w, is);
    // lane covers dims lane*8..+8 -> panel kk=lane>>3, 8B half h of 16B chunk c16
    int kk = lane >> 3, c8 = lane & 7, c16 = c8 >> 1, h = c8 & 1;
    size_t o = (size_t)layer * (NK * NC) + (size_t)kk * (NK * 64) + (size_t)cin * 64
             + (((unsigned)(c16 ^ KEY4(cin)) << 4) + (h << 3));
    *(uint2*)(cbhi + o) = w;
    #pragma unroll
    for (int off = 32; off; off >>= 1) s += __shfl_down(s, off, 64);
    if (lane == 0) { cbn[code] = 0.5f * s; cbs[code] = am * (1.0f / 127.0f); }
}

// -------- x conversion: (B,C,T) fp32 -> panel-major swizzled i8 ----
__global__ __launch_bounds__(256) void vq_cvt_x(const float* __restrict__ x,
                                                unsigned char* __restrict__ xh,
                                                unsigned int* __restrict__ candcnt,
                                                unsigned int* __restrict__ done,
                                                const unsigned* __restrict__ rmax) {
    __shared__ float hs[64][68];                     // [c_local][t_local]
    int bx = blockIdx.x;
    int b = bx >> 5, tt = (bx >> 3) & 3, kk = bx & 7;   // kk = panel (64-dim chunk)
    int c0 = kk << 6, t0 = tt << 6, tid = threadIdx.x;
    if (kk == 0 && tid < 64) candcnt[b * 256 + t0 + tid] = 0u;  // layer-0 init
    if (bx == 0 && tid == 0) *done = 0u;
    const float is = 127.0f / __uint_as_float(rmax[0]);
    const float* base = x + (size_t)b * (NC * NT) + t0;
    #pragma unroll
    for (int i = 0; i < 4; ++i) {
        int f = tid + (i << 8);
        int c_l = f >> 4, t4 = f & 15;
        float4 v = *(const float4*)(base + (size_t)(c0 + c_l) * NT + (t4 << 2));
        *(float4*)&hs[c_l][t4 << 2] = v;
    }
    __syncthreads();
    int row0 = b * NT + t0;
    int r_l = tid >> 2, c16 = tid & 3;               // 64 rows x 4 chunks
    float v[16];
    #pragma unroll
    for (int j = 0; j < 16; ++j) v[j] = hs[c16 * 16 + j][r_l];
    uint4 w;
    w.x = pack4i8(v[0],  v[1],  v[2],  v[3],  is);
    w.y = pack4i8(v[4],  v[5],  v[6],  v[7],  is);
    w.z = pack4i8(v[8],  v[9],  v[10], v[11], is);
    w.w = pack4i8(v[12], v[13], v[14], v[15], is);
    *(uint4*)(xh + (((size_t)kk * NROWS + row0 + r_l) << 6)
                 + ((unsigned)(c16 ^ KEY4(r_l)) << 4)) = w;
}

// -------- i8 MFMA approx distance + (code,score) candidate emission --------
// 256x256 tile, 8 waves, BK=64 (one panel), 4-deep LDS pipeline (4 x 32 KiB),
// counted vmcnt(12) + raw barriers; panel-major contiguous staging bursts.
// Each 16B ds_read feeds TWO mfma_i32_16x16x32_i8 (8B halves; A/B use the
// same physical-k split so the int32 reduction is exact).
__global__ __launch_bounds__(512, 2) void vq_dist(
    const unsigned char* __restrict__ xh, const unsigned char* __restrict__ ch,
    const float* __restrict__ cbn, const float* __restrict__ cbs,
    const unsigned* __restrict__ rmax,
    unsigned int* __restrict__ cand, unsigned int* __restrict__ candcnt,
    unsigned int* __restrict__ counts, float* __restrict__ commit_slot, int q)
{
    extern __shared__ unsigned char smem[];   // 4 bufs x (A 16K + B 16K) = 128 KiB
    const int rb = blockIdx.x, cg = blockIdx.y, tid = threadIdx.x;
    if (rb == 0 && cg == 0) {     // init for rescore/update of this layer
        for (int i = tid; i < NK; i += 512) counts[i] = 0u;
        if (tid == 0) *commit_slot = 0.f;
    }
    // x-side scale (must match the emission scale used by cvt_x / update(q-1))
    const float sx = ((q == 0) ? __uint_as_float(rmax[0])
                               : 1.5f * __uint_as_float(rmax[q - 1])) * (1.0f / 127.0f);
    const int wave = tid >> 6, lane = tid & 63;
    const int idx16 = lane & 15, quad = lane >> 4;
    const int wm = wave >> 2, wn = wave & 3;
    const int m0 = rb * 256, n0 = cg * 256;

    // staging: waves 0-3 -> A (xh rows m0..), waves 4-7 -> B (ch rows n0..)
    const unsigned char* gsrc = (wave < 4) ? xh : ch;
    const int tbase = (wave < 4) ? m0 : n0;
    const size_t strideK = (size_t)((wave < 4) ? NROWS : NK) << 6;   // bytes per panel
    const unsigned char* gp = gsrc + ((size_t)(tbase + ((wave & 3) << 6)) << 6) + lane * 16;
    unsigned char* lp0 = &smem[((wave < 4) ? 0 : 16384) + ((wave & 3) << 12) + lane * 16];

    // per-wave LDS read bases (KEY4 reduces to idx16-only: bases are mult of 16)
    const unsigned slot = (unsigned)((quad ^ KEY4(idx16)) << 4);
    const unsigned aB0 = lds_addr(&smem[(wm * 128 + idx16) * 64]) + slot;
    const unsigned bB0 = lds_addr(&smem[16384 + (wn * 64 + idx16) * 64]) + slot;

    i32x4 acc[8][4];
    #pragma unroll
    for (int mt = 0; mt < 8; ++mt)
        #pragma unroll
        for (int nt = 0; nt < 4; ++nt) acc[mt][nt] = (i32x4){0, 0, 0, 0};

    #define STAGE(KK) {                                                        \
        const unsigned char* g = gp + (size_t)(KK) * strideK;                  \
        unsigned char* lp = lp0 + (((KK) & 3) << 15);                          \
        load_lds16(g,        lp);        load_lds16(g + 1024, lp + 1024);      \
        load_lds16(g + 2048, lp + 2048); load_lds16(g + 3072, lp + 3072); }

    STAGE(0); STAGE(1); STAGE(2);        // 3-deep prologue (12 loads in flight)

    #pragma unroll
    for (int k = 0; k < 8; ++k) {
        if (k < 5) {
            STAGE(k + 3);
            asm volatile("s_waitcnt vmcnt(12)" ::: "memory");  // step k landed
        } else if (k == 5) {
            asm volatile("s_waitcnt vmcnt(8)" ::: "memory");
        } else if (k == 6) {
            asm volatile("s_waitcnt vmcnt(4)" ::: "memory");
        } else {
            asm volatile("s_waitcnt vmcnt(0)" ::: "memory");
        }
        __builtin_amdgcn_s_barrier();
        __builtin_amdgcn_sched_barrier(0);
        {
            const unsigned boff = (unsigned)((k & 3) << 15);
            const unsigned ab = aB0 + boff, bb = bB0 + boff;
            union { i32x4 v; long l[2]; } a[8], b[4];
            DSR(a[0].v, ab, 0);    DSR(a[1].v, ab, 1024);
            DSR(a[2].v, ab, 2048); DSR(a[3].v, ab, 3072);
            DSR(a[4].v, ab, 4096); DSR(a[5].v, ab, 5120);
            DSR(a[6].v, ab, 6144); DSR(a[7].v, ab, 7168);
            DSR(b[0].v, bb, 0);    DSR(b[1].v, bb, 1024);
            DSR(b[2].v, bb, 2048); DSR(b[3].v, bb, 3072);
            asm volatile("s_waitcnt lgkmcnt(0)" ::: "memory");
            __builtin_amdgcn_sched_barrier(0);
            __builtin_amdgcn_s_setprio(1);
            #pragma unroll
            for (int h = 0; h < 2; ++h)
                #pragma unroll
                for (int mt = 0; mt < 8; ++mt)
                    #pragma unroll
                    for (int nt = 0; nt < 4; ++nt)
                        acc[mt][nt] = __builtin_amdgcn_mfma_i32_16x16x32_i8(
                            a[mt].l[h], b[nt].l[h], acc[mt][nt], 0, 0, 0);
            __builtin_amdgcn_s_setprio(0);
            __builtin_amdgcn_sched_barrier(0);
        }
        __builtin_amdgcn_s_barrier();
        __builtin_amdgcn_sched_barrier(0);
    }
    #undef STAGE

    // epilogue: per-row wave-min over this wave's 64 codes, delta-window emission
    float cn[4], sl[4]; int ng[4];
    #pragma unroll
    for (int nt = 0; nt < 4; ++nt) {
        ng[nt] = n0 + wn * 64 + nt * 16 + idx16;
        cn[nt] = cbn[ng[nt]];
        sl[nt] = sx * cbs[ng[nt]];
    }
    #pragma unroll
    for (int mt = 0; mt < 8; ++mt) {
        #pragma unroll
        for (int r = 0; r < 4; ++r) {
            float sc[4];
            float m = 3.402823466e38f;
            #pragma unroll
            for (int nt = 0; nt < 4; ++nt) {
                sc[nt] = cn[nt] - sl[nt] * (float)acc[mt][nt][r];
                m = fminf(m, sc[nt]);
            }
            #pragma unroll
            for (int sft = 1; sft < 16; sft <<= 1)
                m = fminf(m, __shfl_xor(m, sft, 64));
            m += DELTA;
            const int row = m0 + wm * 128 + mt * 16 + quad * 4 + r;
            #pragma unroll
            for (int nt = 0; nt < 4; ++nt) {
                if (sc[nt] <= m) {
                    unsigned slot2 = atomicAdd(&candcnt[row], 1u);
                    if (slot2 < (unsigned)CAP)
                        ((uint2*)cand)[(size_t)row * CAP + slot2] =
                            make_uint2((unsigned)ng[nt], __float_as_uint(sc[nt]));
                }
            }
        }
    }
}

// -------- exact fp32 rescore: global-min filter, then argmin + histogram ----
// grid 1024 blocks (16 rows each), 256 threads = 4 waves, 4 rows/wave.
// Overflow safety: if a row emitted more than CAP candidates, fall back to a
// full 1024-code exact scan for that row (correctness independent of DELTA
// emission-count estimates).
__global__ __launch_bounds__(256) void vq_rescore(
    const float* __restrict__ src,     // residual (B,C,T) current layer input
    const float* __restrict__ cb, const float* __restrict__ cbn,
    const unsigned int* __restrict__ cand, const unsigned int* __restrict__ candcnt,
    int* __restrict__ best_idx, float* __restrict__ out_idx,
    unsigned int* __restrict__ counts, int q)
{
    __shared__ float xl[16][512];      // [t_local][c], 32 KiB
    const int tid = threadIdx.x;
    const int b = blockIdx.x >> 4, t0 = (blockIdx.x & 15) << 4;
    const float* base = src + (size_t)b * (NC * NT) + t0;
    #pragma unroll
    for (int i = 0; i < 8; ++i) {
        int f = tid + (i << 8);
        int c = f >> 2, t4 = f & 3;
        float4 v = *(const float4*)(base + (size_t)c * NT + (t4 << 2));
        xl[(t4 << 2) + 0][c] = v.x; xl[(t4 << 2) + 1][c] = v.y;
        xl[(t4 << 2) + 2][c] = v.z; xl[(t4 << 2) + 3][c] = v.w;
    }
    __syncthreads();
    const int w = tid >> 6, lane = tid & 63;
    const int row0 = b * NT + t0;
    const uint2* cp = (const uint2*)cand;
    for (int rr = 0; rr < 4; ++rr) {
        const int tl = w * 4 + rr;
        const int row = row0 + tl;
        float4 xa = *(const float4*)&xl[tl][lane << 3];
        float4 xb = *(const float4*)&xl[tl][(lane << 3) + 4];
        int n = (int)candcnt[row];
        float bs = 3.402823466e38f; int bi = 0x7FFFFFFF;
        if (n > CAP) {
            // overflow fallback: exact scan of all 1024 codes (rare)
            for (int code = 0; code < NK; ++code) {
                const float* cr = cb + (size_t)code * NC + (lane << 3);
                float4 ca = *(const float4*)cr;
                float4 cc = *(const float4*)(cr + 4);
                float s = xa.x*ca.x + xa.y*ca.y + xa.z*ca.z + xa.w*ca.w
                        + xb.x*cc.x + xb.y*cc.y + xb.z*cc.z + xb.w*cc.w;
                #pragma unroll
                for (int off = 1; off < 64; off <<= 1) s += __shfl_xor(s, off, 64);
                s = cbn[code] - s;
                if (s < bs || (s == bs && code < bi)) { bs = s; bi = code; }
            }
        } else {
            uint2 pr = make_uint2(0x7FFFFFFFu, 0x7F800000u);   // (code=max, score=+inf)
            if (lane < n) pr = cp[(size_t)row * CAP + lane];
            float scf = __uint_as_float(pr.y);
            float rmin = scf;
            #pragma unroll
            for (int off = 1; off < 64; off <<= 1) rmin = fminf(rmin, __shfl_xor(rmin, off, 64));
            unsigned long long msk = __ballot(scf <= rmin + DELTA);
            while (msk) {
                int j = (int)__ffsll(msk) - 1; msk &= msk - 1;
                int code = __shfl((int)pr.x, j, 64);
                const float* cr = cb + (size_t)code * NC + (lane << 3);
                float4 ca = *(const float4*)cr;
                float4 cc = *(const float4*)(cr + 4);
                float s = xa.x*ca.x + xa.y*ca.y + xa.z*ca.z + xa.w*ca.w
                        + xb.x*cc.x + xb.y*cc.y + xb.z*cc.z + xb.w*cc.w;
                #pragma unroll
                for (int off = 1; off < 64; off <<= 1) s += __shfl_xor(s, off, 64);
                s = cbn[code] - s;
                if (s < bs || (s == bs && code < bi)) { bs = s; bi = code; }
            }
        }
        if (lane == 0) {
            best_idx[row] = bi;
            out_idx[(size_t)row * NQ + q] = (float)bi;
            atomicAdd(&counts[bi], 1u);
        }
    }
}

// -------- gather + residual update + commit + i8 emit + FUSED stats --------
// grid 256 blocks (64 rows each), 256 threads; last block computes perp/cmean.
// Emits r_{q+1} as i8 with pipelined scale 1.5*rmax[q]/127 and atomicMax's
// rmax[q+1]. At q==NQ-1: writes qout = x - n directly (finalize fold), no emit.
__global__ __launch_bounds__(256) void vq_update(
    const float* __restrict__ src,    // residual before (x for q=0), (B,C,T)
    float* __restrict__ dst,          // residual after (qout slot); last layer: qout
    const float* __restrict__ x,      // original input (for last-layer qout)
    const float* __restrict__ cb,
    const int* __restrict__ best_idx,
    unsigned char* __restrict__ xh,   // i8 residual for next layer's dist
    unsigned* __restrict__ rmax,
    unsigned int* __restrict__ candcnt,
    unsigned int* __restrict__ counts,
    float* __restrict__ csum, float* __restrict__ cmean, float* __restrict__ perp,
    float* __restrict__ out_tail, unsigned int* __restrict__ done, int q)
{
    const int rb = blockIdx.x, tid = threadIdx.x;
    const int b = rb >> 2, t0 = (rb & 3) << 6;
    const int row0 = rb * 64;                    // = b*256 + t0
    __shared__ int s_idx[64];
    __shared__ __align__(16) float qt[64][68];   // [c_local][t_local]
    __shared__ float wsum[4], wmax[4];
    __shared__ unsigned int lastflag;
    if (tid < 64) {
        s_idx[tid] = best_idx[row0 + tid];
        candcnt[row0 + tid] = 0u;                // reset for next layer's dist
    }
    const float emit_is = (q < NQ - 1)
        ? 127.0f / (1.5f * __uint_as_float(rmax[q])) : 0.f;
    __syncthreads();
    float cs = 0.f, am = 0.f;
    const size_t base = (size_t)b * (NC * NT) + t0;
    for (int ct = 0; ct < 8; ++ct) {             // c chunks of 64 (= panel kk)
        if (ct) __syncthreads();
        // gather cb[idx[r]] chunk into qt [c][t]
        #pragma unroll
        for (int i = 0; i < 4; ++i) {
            int f = tid + (i << 8);
            int r = f >> 4, cf = f & 15;
            float4 v = *(const float4*)(cb + (size_t)s_idx[r] * NC + ct * 64 + (cf << 2));
            qt[(cf << 2) + 0][r] = v.x;
            qt[(cf << 2) + 1][r] = v.y;
            qt[(cf << 2) + 2][r] = v.z;
            qt[(cf << 2) + 3][r] = v.w;
        }
        __syncthreads();
        // residual RMW (coalesced along t); overwrite qt cells with n in place
        #pragma unroll
        for (int i = 0; i < 4; ++i) {
            int f = tid + (i << 8);
            int c_l = f >> 4, tf = f & 15;
            size_t o = base + (size_t)(ct * 64 + c_l) * NT + (tf << 2);
            float4 r4 = *(const float4*)(src + o);
            float4 q4 = *(const float4*)&qt[c_l][tf << 2];
            float4 n;
            n.x = r4.x - q4.x; n.y = r4.y - q4.y; n.z = r4.z - q4.z; n.w = r4.w - q4.w;
            float4 o4 = n;
            if (q == NQ - 1) {                   // finalize fold: qout = x - n
                float4 xv = *(const float4*)(x + o);
                o4.x = xv.x - n.x; o4.y = xv.y - n.y;
                o4.z = xv.z - n.z; o4.w = xv.w - n.w;
            }
            *(float4*)(dst + o) = o4;
            *(float4*)&qt[c_l][tf << 2] = n;
            cs += n.x*n.x + n.y*n.y + n.z*n.z + n.w*n.w;
            am = fmaxf(am, fmaxf(fmaxf(fabsf(n.x), fabsf(n.y)),
                                 fmaxf(fabsf(n.z), fabsf(n.w))));
        }
        if (q < NQ - 1) {
            __syncthreads();
            // transpose-read n, pack i8, panel-major swizzled emit
            int r_l = tid >> 2, c16 = tid & 3;
            float v[16];
            #pragma unroll
            for (int j = 0; j < 16; ++j) v[j] = qt[c16 * 16 + j][r_l];
            uint4 w;
            w.x = pack4i8(v[0],  v[1],  v[2],  v[3],  emit_is);
            w.y = pack4i8(v[4],  v[5],  v[6],  v[7],  emit_is);
            w.z = pack4i8(v[8],  v[9],  v[10], v[11], emit_is);
            w.w = pack4i8(v[12], v[13], v[14], v[15], emit_is);
            *(uint4*)(xh + (((size_t)ct * NROWS + row0 + r_l) << 6)
                         + ((unsigned)(c16 ^ KEY4(r_l)) << 4)) = w;
        }
    }
    #pragma unroll
    for (int off = 32; off; off >>= 1) {
        cs += __shfl_down(cs, off, 64);
        am = fmaxf(am, __shfl_down(am, off, 64));
    }
    if ((tid & 63) == 0) { wsum[tid >> 6] = cs; wmax[tid >> 6] = am; }
    __syncthreads();
    if (tid == 0) {
        if (q < NQ - 1)
            atomicMax(&rmax[q + 1], __float_as_uint(
                fmaxf(fmaxf(wmax[0], wmax[1]), fmaxf(wmax[2], wmax[3]))));
        atomicAdd(&csum[q], wsum[0] + wsum[1] + wsum[2] + wsum[3]);
        __threadfence();
        lastflag = atomicAdd(done, 1u);
    }
    __syncthreads();
    if (lastflag == 255u) {                      // last block: fused per-layer stats
        float v = 0.f;
        for (int i = tid; i < NK; i += 256) {
            float p = (float)atomicAdd(&counts[i], 0u) * (1.f / (float)NROWS);
            v += p * logf(p + 1e-7f);
        }
        #pragma unroll
        for (int off = 32; off; off >>= 1) v += __shfl_down(v, off, 64);
        if ((tid & 63) == 0) wsum[tid >> 6] = v;
        __syncthreads();
        if (tid == 0) {
            float S = wsum[0] + wsum[1] + wsum[2] + wsum[3];
            perp[q]  = expf(-S);
            cmean[q] = atomicAdd(&csum[q], 0.f) * (1.f / ((float)NROWS * (float)NC));
            if (q == NQ - 1) {
                float mc = 0.f, mp = 0.f;
                for (int i = 0; i < NQ; ++i) { mc += cmean[i]; mp += perp[i]; }
                out_tail[0] = mc / (float)NQ;
                out_tail[1] = mp / (float)NQ;
            }
            *done = 0u;                          // reset for next layer
        }
    }
}

extern "C" void kernel_launch(void* const* d_in, const int* in_sizes, int n_in,
                              void* d_out, int out_size, void* d_ws, size_t ws_size,
                              hipStream_t stream) {
    static int inited = 0;
    if (!inited) {
        // allow 128 KiB dynamic LDS for vq_dist (gfx950 has 160 KiB/CU)
        (void)hipFuncSetAttribute((const void*)vq_dist,
                                  hipFuncAttributeMaxDynamicSharedMemorySize, 131072);
        inited = 1;
    }
    const float* x  = (const float*)d_in[0];
    const float* cb = (const float*)d_in[1];       // (Q,K,C)
    float* out      = (float*)d_out;
    float* res      = out;                          // residual lives in qout slot
    float* out_idx  = out + QOUT_ELEMS;
    float* out_tail = out + QOUT_ELEMS + IDX_ELEMS;
    char* ws = (char*)d_ws;
    unsigned int* cand    = (unsigned int*)(ws + WS_CAND);
    unsigned int* candcnt = (unsigned int*)(ws + WS_CCNT);
    int*          bidx    = (int*)(ws + WS_BIDX);
    unsigned int* counts  = (unsigned int*)(ws + WS_COUNTS);
    float* csum  = (float*)(ws + WS_CSUM);
    float* cmean = (float*)(ws + WS_CMEAN);
    float* perp  = (float*)(ws + WS_PERP);
    unsigned int* done = (unsigned int*)(ws + WS_DONE);
    unsigned* rmax = (unsigned*)(ws + WS_RMAX);
    float* cbn   = (float*)(ws + WS_CBN);
    float* cbs   = (float*)(ws + WS_CBS);
    unsigned char* xh   = (unsigned char*)(ws + WS_XHI);
    unsigned char* cbhi = (unsigned char*)(ws + WS_CBHI);

    hipMemsetAsync(ws + WS_RMAX, 0, 32, stream);
    vq_xmax<<<1024, 256, 0, stream>>>(x, rmax);
    vq_cvt_cb<<<1536, 256, 0, stream>>>(cb, cbhi, cbn, cbs);
    vq_cvt_x<<<2048, 256, 0, stream>>>(x, xh, candcnt, done, rmax);
    for (int q = 0; q < NQ; ++q) {
        const float* src = (q == 0) ? x : res;
        const float* cbq = cb + (size_t)q * NK * NC;
        vq_dist<<<dim3(64, 4), 512, 131072, stream>>>(
            xh, cbhi + (size_t)q * (NK * NC), cbn + q * NK, cbs + q * NK, rmax,
            cand, candcnt, counts, csum + q, q);
        vq_rescore<<<1024, 256, 0, stream>>>(src, cbq, cbn + q * NK, cand, candcnt,
                                             bidx, out_idx, counts, q);
        vq_update<<<256, 256, 0, stream>>>(src, res, x, cbq, bidx, xh, rmax, candcnt,
                                           counts, csum, cmean, perp, out_tail, done, q);
    }
}